// Round 6
// baseline (328.950 us; speedup 1.0000x reference)
//
#include <hip/hip_runtime.h>
#include <hip/hip_cooperative_groups.h>
#include <math.h>

namespace cg = cooperative_groups;

#define NROWS 8192   // BATCH*NODE
#define DIM   128
#define FEAT  256
#define BK    128
#define NT    (NROWS / BK)   // 64 K-tiles in gemm1

typedef __attribute__((ext_vector_type(8))) __bf16 bf16x8;
typedef __attribute__((ext_vector_type(8))) unsigned short u16x8;
typedef __attribute__((ext_vector_type(4))) unsigned short u16x4;
typedef __attribute__((ext_vector_type(4))) float f32x4;

__device__ __forceinline__ float bf2f(unsigned short h) {
  return __uint_as_float(((unsigned)h) << 16);
}
__device__ __forceinline__ unsigned short f2bf(float f) {
  unsigned u = __float_as_uint(f);
  return (unsigned short)((u + 0x7fff + ((u >> 16) & 1)) >> 16);  // RNE
}
__device__ __forceinline__ void async16(const void* g, void* l) {
  __builtin_amdgcn_global_load_lds(
      (const __attribute__((address_space(1))) void*)g,
      (__attribute__((address_space(3))) void*)l, 16, 0, 0);
}
__device__ __forceinline__ f32x4 mfma16(bf16x8 a, bf16x8 b, f32x4 c) {
  return __builtin_amdgcn_mfma_f32_16x16x32_bf16(a, b, c, 0, 0, 0);
}
__device__ __forceinline__ float ldp(const void* p, int i, int is32) {
  return is32 ? ((const float*)p)[i] : bf2f(((const unsigned short*)p)[i]);
}

// ---------------------------------------------------------------------------
// P1: fused transpose (256 blocks x 32 rows, 512 threads): raw input ->
// inpc (bf16 copy), x0 (elu'd), xT (128x8192 transposed elu'd), x-part
// column stats (atomics into pre-zeroed stats[0..127], [256..383]).
// ---------------------------------------------------------------------------
__device__ __forceinline__ void trans_phase(
    const void* __restrict__ src, unsigned short* __restrict__ xT,
    unsigned short* __restrict__ x0, unsigned short* __restrict__ inpc,
    float* __restrict__ stats, int is32, char* smemraw, int bid, int tid)
{
  unsigned short* T = (unsigned short*)smemraw;   // 32 x 136 (pad 128->136)
  const int r0 = bid * 32;
  {
    const int rr = tid >> 4, cg = tid & 15;       // 512 chunks, 1/thread
    const size_t gidx = (size_t)(r0 + rr) * DIM + cg * 8;
    u16x8 v;
    if (is32) {
      const float* s = (const float*)src + gidx;
      f32x4 a = *(const f32x4*)s, b = *(const f32x4*)(s + 4);
      #pragma unroll
      for (int e = 0; e < 4; e++) { v[e] = f2bf(a[e]); v[e + 4] = f2bf(b[e]); }
    } else {
      v = *(const u16x8*)((const unsigned short*)src + gidx);
    }
    *(u16x8*)(inpc + gidx) = v;            // raw copy for residual
    #pragma unroll
    for (int e = 0; e < 8; e++) {
      float f = bf2f(v[e]);
      f = f > 0.f ? f : expm1f(f);
      v[e] = f2bf(f);
    }
    *(u16x8*)(x0 + gidx) = v;              // elu'd x for gemm2
    *(u16x8*)(T + rr * 136 + cg * 8) = v;
  }
  __syncthreads();
  {
    const int n = tid >> 2, mg = tid & 3;  // feature n, 8-row group mg
    u16x8 v;
    float s = 0.f, q = 0.f;
    #pragma unroll
    for (int e = 0; e < 8; e++) {
      unsigned short h = T[(mg * 8 + e) * 136 + n];
      v[e] = h;
      float f = bf2f(h);
      s += f; q += f * f;
    }
    *(u16x8*)(xT + (size_t)n * NROWS + r0 + mg * 8) = v;
    #pragma unroll
    for (int off = 1; off < 4; off <<= 1) {
      s += __shfl_xor(s, off, 4);
      q += __shfl_xor(q, off, 4);
    }
    if ((tid & 3) == 0) {
      atomicAdd(&stats[n], s);
      atomicAdd(&stats[256 + n], q);
    }
  }
}

// ---------------------------------------------------------------------------
// P2/P4: GEMM1 fused: Lx[m0:m0+32, :] = L[m0:m0+32, :] @ x  (full K = 8192)
// Depth-2 software pipeline: triple-buffered B (and A) tiles, counted
// s_waitcnt vmcnt(N) + raw s_barrier per K-step (never drains newest tile).
// 16x16x32 MFMA, 8 waves = 2 M-halves x 4 N-quads, two independent acc
// chains per wave. NO setprio (hurts lockstep GEMM — r5 A/B + m190).
// L read as f32 (reg-staged + cvt) or bf16 (global_load_lds).
// Epilogue: Lx -> bf16 Lxb + column stats (atomics, features 128..255).
// LDS 16B chunks XOR-swizzled: phys p = (kg&8)|((kg&7)^(row&7)) both sides.
// ---------------------------------------------------------------------------
template <int IS32>
__device__ __forceinline__ void gemm1_body(
    const void* __restrict__ Lraw, const unsigned short* __restrict__ xT,
    unsigned short* __restrict__ Lxb, float* __restrict__ stats,
    unsigned short* __restrict__ AsBase, unsigned short* __restrict__ BsBase)
{
  const int tid  = threadIdx.x;          // 0..511
  const int lane = tid & 63;
  const int wave = tid >> 6;             // 0..7
  const int wm = wave >> 2, wn = wave & 3;   // 2 x 4 wave grid
  const int ln = lane & 15, quad = lane >> 4;
  const int m0 = blockIdx.x * 32;

  // A staging coords: 512 chunks of 16B (32 rows x 16 chunks), 1/thread
  const int arow = tid >> 4, ap = tid & 15;
  const int akg = (ap & 8) | ((ap & 7) ^ (arow & 7));   // global k-group
  const float*          Lf = (const float*)Lraw;
  const unsigned short* Lh = (const unsigned short*)Lraw;
  const size_t Abase = (size_t)(m0 + arow) * NROWS + akg * 8;

  // B staging coords: 2048 chunks (128 rows x 16), 4/thread
  int brow[4], bkg[4];
  #pragma unroll
  for (int i = 0; i < 4; i++) {
    const int c = tid + (i << 9);
    brow[i] = c >> 4;
    const int p = c & 15;
    bkg[i] = (p & 8) | ((p & 7) ^ (brow[i] & 7));
  }

  unsigned short* a0 = AsBase;
  unsigned short* a1 = AsBase + 32 * 128;
  unsigned short* a2 = AsBase + 2 * 32 * 128;
  unsigned short* c0 = BsBase;
  unsigned short* c1 = BsBase + 128 * 128;
  unsigned short* c2 = BsBase + 2 * 128 * 128;

  f32x4 acc[2];
  acc[0] = (f32x4){0.f, 0.f, 0.f, 0.f};
  acc[1] = (f32x4){0.f, 0.f, 0.f, 0.f};

  auto issueB = [&](int kt, unsigned short* Bbuf) {
    const size_t koff = (size_t)kt * BK;
    #pragma unroll
    for (int i = 0; i < 4; i++) {
      const int c = tid + (i << 9);
      async16(xT + (size_t)brow[i] * NROWS + koff + bkg[i] * 8, Bbuf + c * 8);
    }
  };
  auto loadA = [&](int kt, f32x4& r0, f32x4& r1) {
    const float* s = Lf + Abase + (size_t)kt * BK;
    r0 = *(const f32x4*)s;
    r1 = *(const f32x4*)(s + 4);
  };
  auto issueA16 = [&](int kt, unsigned short* Abuf) {
    async16(Lh + Abase + (size_t)kt * BK, Abuf + arow * 128 + ap * 8);
  };
  auto writeA = [&](const f32x4& r0, const f32x4& r1, unsigned short* Abuf) {
    u16x8 o;
    #pragma unroll
    for (int e = 0; e < 4; e++) { o[e] = f2bf(r0[e]); o[e + 4] = f2bf(r1[e]); }
    *(u16x8*)(Abuf + arow * 128 + ap * 8) = o;
  };
  auto compute = [&](const unsigned short* Abuf, const unsigned short* Bbuf) {
    const int arf = wm * 16 + ln;
    const int brf = wn * 32 + ln;
    #pragma unroll
    for (int ks = 0; ks < 4; ks++) {
      const int kga = ks * 4 + quad;
      bf16x8 af = *(const bf16x8*)(Abuf + arf * 128 +
                     ((kga & 8) | ((kga & 7) ^ (arf & 7))) * 8);
      #pragma unroll
      for (int j = 0; j < 2; j++) {
        const int rb = brf + j * 16;
        bf16x8 bf = *(const bf16x8*)(Bbuf + rb * 128 +
                       ((kga & 8) | ((kga & 7) ^ (rb & 7))) * 8);
        acc[j] = mfma16(af, bf, acc[j]);
      }
    }
  };
  auto waitbar = [&]() {
    // retire everything except the newest tile's vmem group (6 f32 / 5 bf16)
    if (IS32) asm volatile("s_waitcnt vmcnt(6) lgkmcnt(0)" ::: "memory");
    else      asm volatile("s_waitcnt vmcnt(5) lgkmcnt(0)" ::: "memory");
    __builtin_amdgcn_s_barrier();
  };

  f32x4 e0, e1, o0, o1;   // A f32 reg sets (even-tile / odd-tile destined)

  // ---- prologue: tiles 0 and 1 in flight ----
  issueB(0, c0);
  if (IS32) loadA(0, e0, e1); else issueA16(0, a0);
  issueB(1, c1);
  if (IS32) loadA(1, o0, o1); else issueA16(1, a1);
  if (IS32) writeA(e0, e1, a0);   // auto vmcnt wait covers tile-0 A regs
  waitbar();

  // ---- main: 31 pairs, tiles 0..61, prefetch 2 ahead ----
  for (int p = 0; p < 31; ++p) {
    const int t = 2 * p;
    // even body: tile t (reads a0/c0)
    issueB(t + 2, c2);
    if (IS32) loadA(t + 2, e0, e1); else issueA16(t + 2, a2);
    compute(a0, c0);
    if (IS32) writeA(o0, o1, a1);   // A(t+1) -> next buffer
    waitbar();
    // odd body: tile t+1 (reads a1/c1)
    issueB(t + 3, c0);
    if (IS32) loadA(t + 3, o0, o1); else issueA16(t + 3, a0);
    compute(a1, c1);
    if (IS32) writeA(e0, e1, a2);   // A(t+2) -> future buffer
    waitbar();
    // rotate buffers: (c0,c1,c2) <- (c2,c0,c1)
    unsigned short* tB = c2; c2 = c1; c1 = c0; c0 = tB;
    unsigned short* tA = a2; a2 = a1; a1 = a0; a0 = tA;
  }

  // ---- tail: tiles 62, 63 (already prefetched) ----
  compute(a0, c0);
  if (IS32) writeA(o0, o1, a1);     // A(63)
  __syncthreads();                  // drains remaining tile-63 vmem
  compute(a1, c1);
  __syncthreads();

  // ---- epilogue: acc -> f32 LDS tile (reuses A buffers, 16 KB) ----
  float* E = (float*)AsBase;        // 32 x 128 f32
  #pragma unroll
  for (int j = 0; j < 2; j++) {
    const int col = wn * 32 + j * 16 + ln;
    #pragma unroll
    for (int r = 0; r < 4; r++)
      E[(wm * 16 + quad * 4 + r) * 128 + col] = acc[j][r];
  }
  __syncthreads();
  {  // coalesced bf16 store of Lx
    const int row = tid >> 4, cc0 = (tid & 15) * 8;
    u16x8 o;
    #pragma unroll
    for (int e = 0; e < 8; e++) o[e] = f2bf(E[row * 128 + cc0 + e]);
    *(u16x8*)(Lxb + (size_t)(m0 + row) * DIM + cc0) = o;
  }
  if (tid < 128) {  // column stats (f32 values), features 128..255
    float s = 0.f, q = 0.f;
    #pragma unroll
    for (int r = 0; r < 32; r++) {
      const float v = E[r * 128 + tid];
      s += v; q += v * v;
    }
    atomicAdd(&stats[128 + tid], s);
    atomicAdd(&stats[384 + tid], q);
  }
}

// ---------------------------------------------------------------------------
// P3/P5: GEMM2 with fused BN-fold (512 threads, 8 waves = 2 M-halves x 4
// N-quads): out = ((h - mu)*s) @ w^T + (beta @ w^T + bias)
// stats are COMPLETE sums. mode0: elu -> bf16 x1 + transposed xT + x1 column
// stats (atomics into pre-zeroed statsOut). mode1: + resid -> d_out.
// ---------------------------------------------------------------------------
__device__ __forceinline__ void gemm2_phase(
    const unsigned short* __restrict__ xb,    // 8192x128
    const unsigned short* __restrict__ Lxb,   // 8192x128
    const unsigned short* __restrict__ wb,    // 128x256 bf16 raw weights
    const void* __restrict__ gamma, const void* __restrict__ beta,
    const void* __restrict__ bias,
    const float* __restrict__ stats,          // 512 complete sums/sumsq
    const unsigned short* __restrict__ resid, // inpc (mode1) or nullptr
    void* __restrict__ outv,
    unsigned short* __restrict__ xTout,       // mode0 only
    float* __restrict__ statsOut,             // mode0 only
    int mode, int is32, char* smemraw, int bid, int tid)
{
  unsigned short* As = (unsigned short*)smemraw;       // 32*264*2 = 16896 B
  float* sS   = (float*)(smemraw + 20480);             // 256
  float* sMS  = sS + 256;                              // 256
  float* bred = sMS + 256;                             // 512
  float* bv   = bred + 512;                            // 128
  const int lane = tid & 63, wave = tid >> 6;
  const int m0 = bid * 32;

  // ---- per-feature BN scale from complete sums ----
  if (tid < 256) {
    const int j = tid;
    const float inv = 1.f / 8192.f;
    const float mu = stats[j] * inv;
    const float var = fmaxf(stats[256 + j] * inv - mu * mu, 0.f);
    const float sj = ldp(gamma, j, is32) * rsqrtf(var + 1e-5f);
    sS[j] = sj;
    sMS[j] = mu * sj;
  }
  // ---- beta matvec for bias: k = tid&127, quarter = tid>>7 ----
  {
    const int k = tid & 127, qtr = tid >> 7;
    float a = 0.f;
    #pragma unroll
    for (int jj = 0; jj < 64; jj += 8) {
      u16x8 wv = *(const u16x8*)(wb + k * 256 + qtr * 64 + jj);
      #pragma unroll
      for (int e = 0; e < 8; e++)
        a += ldp(beta, qtr * 64 + jj + e, is32) * bf2f(wv[e]);
    }
    bred[tid] = a;
  }
  __syncthreads();
  if (tid < 128)
    bv[tid] = ldp(bias, tid, is32) + bred[tid] + bred[tid + 128] +
              bred[tid + 256] + bred[tid + 384];

  // ---- stage A tile with BN transform: 1024 chunks, 2/thread ----
  #pragma unroll
  for (int i = 0; i < 2; i++) {
    const int c = tid + 512 * i;
    const int mr = c >> 5, ch = c & 31;
    const unsigned short* src =
        (ch < 16) ? (xb  + (size_t)(m0 + mr) * DIM + ch * 8)
                  : (Lxb + (size_t)(m0 + mr) * DIM + (ch - 16) * 8);
    u16x8 v = *(const u16x8*)src;
    const int j0 = ch * 8;
    #pragma unroll
    for (int e = 0; e < 8; e++) {
      const float f = bf2f(v[e]);
      v[e] = f2bf(f * sS[j0 + e] - sMS[j0 + e]);
    }
    *(u16x8*)(As + mr * 264 + ch * 8) = v;
  }
  __syncthreads();   // also orders bv writes before epilogue reads

  const int ln = lane & 15, quad = lane >> 4;
  const int wm2 = wave >> 2, wn2 = wave & 3;
  const int nq = wn2 * 32;
  f32x4 acc[2];
  acc[0] = (f32x4){0.f, 0.f, 0.f, 0.f};
  acc[1] = (f32x4){0.f, 0.f, 0.f, 0.f};

  #pragma unroll
  for (int ks = 0; ks < 8; ks++) {
    bf16x8 af = *(const bf16x8*)(As + (wm2 * 16 + ln) * 264 + ks * 32 +
                                 quad * 8);
    #pragma unroll
    for (int j = 0; j < 2; j++) {
      bf16x8 bfr = *(const bf16x8*)(wb + (size_t)(nq + j * 16 + ln) * FEAT +
                                    ks * 32 + quad * 8);
      acc[j] = mfma16(af, bfr, acc[j]);
    }
  }

  #pragma unroll
  for (int j = 0; j < 2; j++) {
    const int gn = nq + j * 16 + ln;
    const float bb = bv[gn];
    float s = 0.f, q = 0.f;
    u16x4 pk;
    #pragma unroll
    for (int r = 0; r < 4; r++) {
      const int gm = m0 + wm2 * 16 + quad * 4 + r;
      float v = acc[j][r] + bb;
      const size_t idx = (size_t)gm * DIM + gn;
      if (mode == 0) {
        v = v > 0.f ? v : expm1f(v);
        const unsigned short h = f2bf(v);
        ((unsigned short*)outv)[idx] = h;
        pk[r] = h;
        const float hv = bf2f(h);
        s += hv; q += hv * hv;
      } else {
        v += bf2f(resid[idx]);
        if (is32) ((float*)outv)[idx] = v;
        else      ((unsigned short*)outv)[idx] = f2bf(v);
      }
    }
    if (mode == 0) {
      *(u16x4*)(xTout + (size_t)gn * NROWS + m0 + wm2 * 16 + quad * 4) = pk;
      // sum over quad (16 rows of this half); the other half-wave adds too
      s += __shfl_xor(s, 16); q += __shfl_xor(q, 16);
      s += __shfl_xor(s, 32); q += __shfl_xor(q, 32);
      if (quad == 0) {
        atomicAdd(&statsOut[gn], s);
        atomicAdd(&statsOut[256 + gn], q);
      }
    }
  }
}

// ---------------------------------------------------------------------------
// Single cooperative kernel: P0 detect/zero/weight-cvt -> P1 trans ->
// P2 gemm1a -> P3 gemm2a(mode0) -> P4 gemm1b -> P5 gemm2b(mode1),
// separated by grid.sync(). 256 blocks x 512 threads, 120 KB LDS
// (1 block/CU -> all blocks co-resident).
// dtype detect is block-local: every block reads the same first 8 KB of L
// (f32: ~12.5% of all shorts have bf16-exponent field >= 192; bf16: 0).
// ---------------------------------------------------------------------------
__global__ __launch_bounds__(512) void fused_all(
    const void* __restrict__ Lm, const void* __restrict__ inp,
    const void* __restrict__ bn0g, const void* __restrict__ bn0b,
    const void* __restrict__ fc0w, const void* __restrict__ fc0b,
    const void* __restrict__ bn1g, const void* __restrict__ bn1b,
    const void* __restrict__ fc1w, const void* __restrict__ fc1b,
    void* __restrict__ d_out,
    unsigned short* __restrict__ xT, unsigned short* __restrict__ x0,
    unsigned short* __restrict__ Lxb, unsigned short* __restrict__ x1,
    unsigned short* __restrict__ inpc,
    float* __restrict__ stats, unsigned short* __restrict__ wb)
{
  __shared__ __align__(16) char smem[122880];   // 120 KB overlay
  __shared__ int cnt;
  cg::grid_group grid = cg::this_grid();
  const int tid = threadIdx.x;
  const int bid = blockIdx.x;

  // ---- P0: block-local dtype detect + zero stats + weight cvt ----
  if (tid == 0) cnt = 0;
  __syncthreads();
  {
    const unsigned short* u = (const unsigned short*)Lm;
    int c = 0;
    #pragma unroll
    for (int i = 0; i < 8; i++) {
      int e = (u[tid * 8 + i] >> 7) & 0xFF;
      if (e >= 192) c++;
    }
    atomicAdd(&cnt, c);
  }
  __syncthreads();
  const int is32 = (cnt > 16);
  if (bid == 0) { stats[tid] = 0.f; stats[tid + 512] = 0.f; }
  if (bid < 8) {   // convert both FC weight matrices to bf16 (w0 | w1)
    const int base = bid * 8192;
    for (int i = tid; i < 8192; i += 512) {
      const int g = base + i;
      const float v = (g < 32768) ? ldp(fc0w, g, is32)
                                  : ldp(fc1w, g - 32768, is32);
      wb[g] = f2bf(v);
    }
  }
  grid.sync();

  // ---- P1: trans ----
  trans_phase(inp, xT, x0, inpc, stats, is32, smem, bid, tid);
  grid.sync();

  // ---- P2: gemm1a ----
  {
    unsigned short* As = (unsigned short*)smem;            // 24 KB
    unsigned short* Bs = (unsigned short*)(smem + 24576);  // 96 KB
    if (is32) gemm1_body<1>(Lm, xT, Lxb, stats, As, Bs);
    else      gemm1_body<0>(Lm, xT, Lxb, stats, As, Bs);
  }
  grid.sync();

  // ---- P3: gemm2a (mode0: x1, xT(x1), statsB) ----
  gemm2_phase(x0, Lxb, wb, bn0g, bn0b, fc0b, stats, nullptr, x1,
              xT, stats + 512, 0, is32, smem, bid, tid);
  grid.sync();

  // ---- P4: gemm1b ----
  {
    unsigned short* As = (unsigned short*)smem;
    unsigned short* Bs = (unsigned short*)(smem + 24576);
    if (is32) gemm1_body<1>(Lm, xT, Lxb, stats + 512, As, Bs);
    else      gemm1_body<0>(Lm, xT, Lxb, stats + 512, As, Bs);
  }
  grid.sync();

  // ---- P5: gemm2b (mode1: residual + output) ----
  gemm2_phase(x1, Lxb, wb + 32768, bn1g, bn1b, fc1b, stats + 512, inpc,
              d_out, nullptr, nullptr, 1, is32, smem, bid, tid);
}

// ---------------------------------------------------------------------------
extern "C" void kernel_launch(void* const* d_in, const int* in_sizes, int n_in,
                              void* d_out, int out_size, void* d_ws, size_t ws_size,
                              hipStream_t stream) {
  const void* Lm   = d_in[0];
  // d_in[1] = mask (unused)
  const void* inp  = d_in[2];
  const void* bn0g = d_in[3];
  const void* bn0b = d_in[4];
  const void* fc0w = d_in[5];
  const void* fc0b = d_in[6];
  const void* bn1g = d_in[7];
  const void* bn1b = d_in[8];
  const void* fc1w = d_in[9];
  const void* fc1b = d_in[10];

  char* ws = (char*)d_ws;
  unsigned short* xT   = (unsigned short*)(ws);                  // 2 MB
  unsigned short* x0   = (unsigned short*)(ws + (2ull << 20));   // 2 MB
  unsigned short* Lxb  = (unsigned short*)(ws + (4ull << 20));   // 2 MB
  unsigned short* x1   = (unsigned short*)(ws + (6ull << 20));   // 2 MB
  unsigned short* inpc = (unsigned short*)(ws + (8ull << 20));   // 2 MB
  float*          stats= (float*)         (ws + (10ull << 20));  // 2x512 f32
  unsigned short* wb   = (unsigned short*)(ws + (10ull << 20) + 16384); // 128KB

  void* args[] = {
    (void*)&Lm, (void*)&inp,
    (void*)&bn0g, (void*)&bn0b, (void*)&fc0w, (void*)&fc0b,
    (void*)&bn1g, (void*)&bn1b, (void*)&fc1w, (void*)&fc1b,
    (void*)&d_out,
    (void*)&xT, (void*)&x0, (void*)&Lxb, (void*)&x1, (void*)&inpc,
    (void*)&stats, (void*)&wb
  };
  hipLaunchCooperativeKernel((const void*)fused_all, dim3(256), dim3(512),
                             args, 0, stream);
}

// Round 7
// 178.836 us; speedup vs baseline: 1.8394x; 1.8394x over previous
//
#include <hip/hip_runtime.h>
#include <math.h>

#define NROWS 8192   // BATCH*NODE
#define DIM   128
#define FEAT  256
#define BK    128
#define NT    (NROWS / BK)   // 64 K-tiles in gemm1

typedef __attribute__((ext_vector_type(8))) __bf16 bf16x8;
typedef __attribute__((ext_vector_type(8))) unsigned short u16x8;
typedef __attribute__((ext_vector_type(4))) unsigned short u16x4;
typedef __attribute__((ext_vector_type(4))) float f32x4;

__device__ __forceinline__ float bf2f(unsigned short h) {
  return __uint_as_float(((unsigned)h) << 16);
}
__device__ __forceinline__ unsigned short f2bf(float f) {
  unsigned u = __float_as_uint(f);
  return (unsigned short)((u + 0x7fff + ((u >> 16) & 1)) >> 16);  // RNE
}
__device__ __forceinline__ void async16(const void* g, void* l) {
  __builtin_amdgcn_global_load_lds(
      (const __attribute__((address_space(1))) void*)g,
      (__attribute__((address_space(3))) void*)l, 16, 0, 0);
}
__device__ __forceinline__ f32x4 mfma16(bf16x8 a, bf16x8 b, f32x4 c) {
  return __builtin_amdgcn_mfma_f32_16x16x32_bf16(a, b, c, 0, 0, 0);
}
__device__ __forceinline__ float ldp(const void* p, int i, int is32) {
  return is32 ? ((const float*)p)[i] : bf2f(((const unsigned short*)p)[i]);
}

// ---------------------------------------------------------------------------
// dtype detection (f32 L: even shorts are uniform mantissa bits -> ~25% have
// bf16-exponent >= 192; bf16 L: |v|<=0.07 -> exponent < 123 -> count 0).
// Also zeroes both per-block stats buffers (replaces the two memsets).
// ---------------------------------------------------------------------------
__global__ void detect_kernel(const unsigned short* __restrict__ L,
                              int* __restrict__ flag,
                              float* __restrict__ stats)
{
  for (int i = threadIdx.x; i < 1024; i += 256) stats[i] = 0.f;
  __shared__ int cnt;
  if (threadIdx.x == 0) cnt = 0;
  __syncthreads();
  int c = 0;
  for (int i = 0; i < 16; i++) {
    unsigned short s = L[2 * (threadIdx.x + 256 * i)];
    int e = (s >> 7) & 0xFF;
    if (e >= 192) c++;
  }
  atomicAdd(&cnt, c);
  __syncthreads();
  if (threadIdx.x == 0) *flag = (cnt > 16) ? 1 : 0;
}

// ---------------------------------------------------------------------------
// fused first transpose: raw input -> inpc (bf16 copy), x0 (elu'd), xT
// (128x8192 transposed elu'd), + x-part column stats (cols 0..127).
// ---------------------------------------------------------------------------
__global__ __launch_bounds__(256) void trans_kernel(
    const void* __restrict__ src, unsigned short* __restrict__ xT,
    unsigned short* __restrict__ x0, unsigned short* __restrict__ inpc,
    float* __restrict__ stats, const int* __restrict__ flag)
{
  __shared__ __align__(16) unsigned short T[128 * 136];  // pad 128->136
  const int tid = threadIdx.x;
  const int r0 = blockIdx.x * 128;
  const int is32 = *flag;
  #pragma unroll
  for (int i = 0; i < 8; i++) {
    const int c = tid + 256 * i;           // 0..2047
    const int rr = c >> 4, cg = c & 15;
    const size_t gidx = (size_t)(r0 + rr) * DIM + cg * 8;
    u16x8 v;
    if (is32) {
      const float* s = (const float*)src + gidx;
      f32x4 a = *(const f32x4*)s, b = *(const f32x4*)(s + 4);
      #pragma unroll
      for (int e = 0; e < 4; e++) { v[e] = f2bf(a[e]); v[e + 4] = f2bf(b[e]); }
    } else {
      v = *(const u16x8*)((const unsigned short*)src + gidx);
    }
    *(u16x8*)(inpc + gidx) = v;            // raw copy for residual
    #pragma unroll
    for (int e = 0; e < 8; e++) {
      float f = bf2f(v[e]);
      f = f > 0.f ? f : expm1f(f);
      v[e] = f2bf(f);
    }
    *(u16x8*)(x0 + gidx) = v;              // elu'd x for gemm2
    *(u16x8*)(T + rr * 136 + cg * 8) = v;
  }
  __syncthreads();
  #pragma unroll
  for (int i = 0; i < 8; i++) {
    const int c = tid + 256 * i;
    const int n = c >> 4, mg = c & 15;     // n = feature, mg = 8-row group
    u16x8 v;
    float s = 0.f, q = 0.f;
    #pragma unroll
    for (int e = 0; e < 8; e++) {
      unsigned short h = T[(mg * 8 + e) * 136 + n];
      v[e] = h;
      float f = bf2f(h);
      s += f; q += f * f;
    }
    *(u16x8*)(xT + (size_t)n * NROWS + r0 + mg * 8) = v;
    #pragma unroll
    for (int off = 1; off < 16; off <<= 1) {
      s += __shfl_xor(s, off, 16);
      q += __shfl_xor(q, off, 16);
    }
    if ((tid & 15) == 0) {
      atomicAdd(&stats[n], s);
      atomicAdd(&stats[256 + n], q);
    }
  }
}

// ---------------------------------------------------------------------------
// GEMM1 fused: Lx[m0:m0+32, :] = L[m0:m0+32, :] @ x  (full K = 8192)
// Depth-2 software pipeline: triple-buffered B (and A) tiles, counted
// s_waitcnt vmcnt(N) + raw s_barrier per K-step (never drains newest tile).
// Wave decomposition: 8 waves = 2 K-halves (kh) x 4 N-quads (wq); each wave
// computes 32m x 32n x 64k per step = 8 MFMA from 8 frag reads (vs 12 in the
// old 2x4 M/N split) with a 4-chain acc[2][2] for MFMA-latency ILP.
// K-halves are reduced through the epilogue LDS tile.
// L read directly as f32 (reg-staged + cvt) or bf16 (global_load_lds).
// Epilogue: Lx -> bf16 Lxb + column stats (features 128..255).
// LDS 16B chunks XOR-swizzled: phys p = (kg&8)|((kg&7)^(row&7)), applied
// identically on staging and read sides.
// ---------------------------------------------------------------------------
template <int IS32>
__device__ __forceinline__ void gemm1_body(
    const void* __restrict__ Lraw, const unsigned short* __restrict__ xT,
    unsigned short* __restrict__ Lxb, float* __restrict__ stats,
    unsigned short* __restrict__ AsBase, unsigned short* __restrict__ BsBase)
{
  const int tid  = threadIdx.x;          // 0..511
  const int lane = tid & 63;
  const int wave = tid >> 6;             // 0..7
  const int kh = wave >> 2, wq = wave & 3;   // K-half x N-quad
  const int ln = lane & 15, quad = lane >> 4;
  const int m0 = blockIdx.x * 32;

  // A staging coords: 512 chunks of 16B (32 rows x 16 chunks), 1/thread
  const int arow = tid >> 4, ap = tid & 15;
  const int akg = (ap & 8) | ((ap & 7) ^ (arow & 7));   // global k-group
  const float*          Lf = (const float*)Lraw;
  const unsigned short* Lh = (const unsigned short*)Lraw;
  const size_t Abase = (size_t)(m0 + arow) * NROWS + akg * 8;

  // B staging coords: 2048 chunks (128 rows x 16), 4/thread
  int brow[4], bkg[4];
  #pragma unroll
  for (int i = 0; i < 4; i++) {
    const int c = tid + (i << 9);
    brow[i] = c >> 4;
    const int p = c & 15;
    bkg[i] = (p & 8) | ((p & 7) ^ (brow[i] & 7));
  }

  unsigned short* a0 = AsBase;
  unsigned short* a1 = AsBase + 32 * 128;
  unsigned short* a2 = AsBase + 2 * 32 * 128;
  unsigned short* c0 = BsBase;
  unsigned short* c1 = BsBase + 128 * 128;
  unsigned short* c2 = BsBase + 2 * 128 * 128;

  f32x4 acc[2][2];
  #pragma unroll
  for (int i = 0; i < 2; i++)
    #pragma unroll
    for (int j = 0; j < 2; j++)
      acc[i][j] = (f32x4){0.f, 0.f, 0.f, 0.f};

  auto issueB = [&](int kt, unsigned short* Bbuf) {
    const size_t koff = (size_t)kt * BK;
    #pragma unroll
    for (int i = 0; i < 4; i++) {
      const int c = tid + (i << 9);
      async16(xT + (size_t)brow[i] * NROWS + koff + bkg[i] * 8, Bbuf + c * 8);
    }
  };
  auto loadA = [&](int kt, f32x4& r0, f32x4& r1) {
    const float* s = Lf + Abase + (size_t)kt * BK;
    r0 = *(const f32x4*)s;
    r1 = *(const f32x4*)(s + 4);
  };
  auto issueA16 = [&](int kt, unsigned short* Abuf) {
    async16(Lh + Abase + (size_t)kt * BK, Abuf + arow * 128 + ap * 8);
  };
  auto writeA = [&](const f32x4& r0, const f32x4& r1, unsigned short* Abuf) {
    u16x8 o;
    #pragma unroll
    for (int e = 0; e < 4; e++) { o[e] = f2bf(r0[e]); o[e + 4] = f2bf(r1[e]); }
    *(u16x8*)(Abuf + arow * 128 + ap * 8) = o;
  };
  auto compute = [&](const unsigned short* Abuf, const unsigned short* Bbuf) {
    #pragma unroll
    for (int s = 0; s < 2; s++) {
      const int kga = kh * 8 + s * 4 + quad;
      const int sw8 = ((kga & 8) | ((kga & 7) ^ (ln & 7))) * 8;
      // all frag rows are ln mod 8 (row offsets 0,16 and wq*32,+16 are ==0 mod 8)
      bf16x8 af0 = *(const bf16x8*)(Abuf + ln * 128 + sw8);
      bf16x8 af1 = *(const bf16x8*)(Abuf + (16 + ln) * 128 + sw8);
      bf16x8 bf0 = *(const bf16x8*)(Bbuf + (wq * 32 + ln) * 128 + sw8);
      bf16x8 bf1 = *(const bf16x8*)(Bbuf + (wq * 32 + 16 + ln) * 128 + sw8);
      acc[0][0] = mfma16(af0, bf0, acc[0][0]);
      acc[0][1] = mfma16(af0, bf1, acc[0][1]);
      acc[1][0] = mfma16(af1, bf0, acc[1][0]);
      acc[1][1] = mfma16(af1, bf1, acc[1][1]);
    }
  };
  auto waitbar = [&]() {
    // retire everything except the newest tile's vmem group (6 f32 / 5 bf16)
    if (IS32) asm volatile("s_waitcnt vmcnt(6) lgkmcnt(0)" ::: "memory");
    else      asm volatile("s_waitcnt vmcnt(5) lgkmcnt(0)" ::: "memory");
    __builtin_amdgcn_s_barrier();
  };

  f32x4 e0, e1, o0, o1;   // A f32 reg sets (even-tile / odd-tile destined)

  // ---- prologue: tiles 0 and 1 in flight ----
  issueB(0, c0);
  if (IS32) loadA(0, e0, e1); else issueA16(0, a0);
  issueB(1, c1);
  if (IS32) loadA(1, o0, o1); else issueA16(1, a1);
  if (IS32) writeA(e0, e1, a0);   // auto vmcnt wait covers tile-0 A regs
  waitbar();

  // ---- main: 31 pairs, tiles 0..61, prefetch 2 ahead ----
  for (int p = 0; p < 31; ++p) {
    const int t = 2 * p;
    // even body: tile t (reads a0/c0)
    issueB(t + 2, c2);
    if (IS32) loadA(t + 2, e0, e1); else issueA16(t + 2, a2);
    compute(a0, c0);
    if (IS32) writeA(o0, o1, a1);   // A(t+1) -> next buffer
    waitbar();
    // odd body: tile t+1 (reads a1/c1)
    issueB(t + 3, c0);
    if (IS32) loadA(t + 3, o0, o1); else issueA16(t + 3, a0);
    compute(a1, c1);
    if (IS32) writeA(e0, e1, a2);   // A(t+2) -> future buffer
    waitbar();
    // rotate buffers: (c0,c1,c2) <- (c2,c0,c1)
    unsigned short* tB = c2; c2 = c1; c1 = c0; c0 = tB;
    unsigned short* tA = a2; a2 = a1; a1 = a0; a0 = tA;
  }

  // ---- tail: tiles 62, 63 (already prefetched) ----
  compute(a0, c0);
  if (IS32) writeA(o0, o1, a1);     // A(63)
  __syncthreads();                  // drains remaining tile-63 vmem
  compute(a1, c1);
  __syncthreads();

  // ---- epilogue: cross-K-half reduce into f32 LDS tile (reuses A bufs) ----
  float* E = (float*)AsBase;        // 32 x 128 f32 = 16 KB
  #pragma unroll
  for (int i = 0; i < 2; i++)
    #pragma unroll
    for (int j = 0; j < 2; j++)
      if (kh == 0) {
        #pragma unroll
        for (int r = 0; r < 4; r++)
          E[(i * 16 + quad * 4 + r) * 128 + wq * 32 + j * 16 + ln] =
              acc[i][j][r];
      }
  __syncthreads();
  if (kh == 1) {
    #pragma unroll
    for (int i = 0; i < 2; i++)
      #pragma unroll
      for (int j = 0; j < 2; j++)
        #pragma unroll
        for (int r = 0; r < 4; r++)
          E[(i * 16 + quad * 4 + r) * 128 + wq * 32 + j * 16 + ln] +=
              acc[i][j][r];
  }
  __syncthreads();
  {  // coalesced bf16 store of Lx
    const int row = tid >> 4, cc0 = (tid & 15) * 8;
    u16x8 o;
    #pragma unroll
    for (int e = 0; e < 8; e++) o[e] = f2bf(E[row * 128 + cc0 + e]);
    *(u16x8*)(Lxb + (size_t)(m0 + row) * DIM + cc0) = o;
  }
  if (tid < 128) {  // column stats (f32 values), features 128..255
    float s = 0.f, q = 0.f;
    #pragma unroll
    for (int r = 0; r < 32; r++) {
      const float v = E[r * 128 + tid];
      s += v; q += v * v;
    }
    atomicAdd(&stats[128 + tid], s);
    atomicAdd(&stats[384 + tid], q);
  }
}

__global__ __launch_bounds__(512) void gemm1_fused(
    const void* __restrict__ Lraw, const unsigned short* __restrict__ xT,
    unsigned short* __restrict__ Lxb, float* __restrict__ stats,
    const int* __restrict__ flag)
{
  __shared__ __align__(16) unsigned short As[3 * 32 * 128];    // 24 KB
  __shared__ __align__(16) unsigned short Bs[3 * 128 * 128];   // 96 KB
  if (*flag) gemm1_body<1>(Lraw, xT, Lxb, stats, As, Bs);
  else       gemm1_body<0>(Lraw, xT, Lxb, stats, As, Bs);
}

// ---------------------------------------------------------------------------
// fold BN into FC; reads raw-dtype params directly (flag)
// ---------------------------------------------------------------------------
__global__ void prep_kernel(const float* __restrict__ stats,
                            const void* __restrict__ gamma,
                            const void* __restrict__ beta,
                            const void* __restrict__ w,
                            const void* __restrict__ bias,
                            unsigned short* __restrict__ weff,
                            float* __restrict__ beff,
                            const int* __restrict__ flag)
{
  const int is32 = *flag;
  const int k = blockIdx.x;   // 0..127
  const int j = threadIdx.x;  // 0..255
  const float inv = 1.f / 8192.f;
  float mu = stats[j] * inv;
  float var = fmaxf(stats[256 + j] * inv - mu * mu, 0.f);
  float s = ldp(gamma, j, is32) * rsqrtf(var + 1e-5f);
  float wv = ldp(w, k * FEAT + j, is32);
  weff[(size_t)k * FEAT + j] = f2bf(wv * s);
  float term = (ldp(beta, j, is32) - mu * s) * wv;
  __shared__ float red[256];
  red[j] = term;
  __syncthreads();
  for (int off = 128; off > 0; off >>= 1) {
    if (j < off) red[j] += red[j + off];
    __syncthreads();
  }
  if (j == 0) beff[k] = ldp(bias, k, is32) + red[0];
}

// ---------------------------------------------------------------------------
// GEMM2: out = [x | Lxb] @ weff.T + beff
// mode0: elu -> bf16 x1, plus fused transpose write xT and x1 column stats
//        for the NEXT block's BN (replaces the second trans_kernel).
// mode1: + resid -> d_out (bf16 or f32 per flag). M-tile 32, grid 256.
// ---------------------------------------------------------------------------
__global__ __launch_bounds__(256) void gemm2_fc(
    const unsigned short* __restrict__ xb,    // 8192x128
    const unsigned short* __restrict__ Lxb,   // 8192x128
    const unsigned short* __restrict__ weff,  // 128x256
    const float* __restrict__ beff,           // 128
    const unsigned short* __restrict__ resid, // inp_c (mode1) or nullptr
    void* __restrict__ outv,
    unsigned short* __restrict__ xTout,       // mode0 only
    float* __restrict__ statsOut,             // mode0 only
    int mode, const int* __restrict__ flag)
{
  __shared__ __align__(16) unsigned short As[32 * 264];
  const int is32 = *flag;
  const int tid = threadIdx.x;
  const int lane = tid & 63, wave = tid >> 6;
  const int m0 = blockIdx.x * 32;

  #pragma unroll
  for (int i = 0; i < 4; i++) {
    const int c = tid + 256 * i;        // 0..1023 (32 rows x 32 chunks)
    const int mr = c >> 5, ch = c & 31;
    const unsigned short* src =
        (ch < 16) ? (xb  + (size_t)(m0 + mr) * DIM + ch * 8)
                  : (Lxb + (size_t)(m0 + mr) * DIM + (ch - 16) * 8);
    *(u16x8*)(As + mr * 264 + ch * 8) = *(const u16x8*)src;
  }
  __syncthreads();

  const int ln = lane & 15, quad = lane >> 4;
  const int nq = wave * 32;
  f32x4 acc[2][2];
  #pragma unroll
  for (int i = 0; i < 2; i++)
    #pragma unroll
    for (int j = 0; j < 2; j++)
      acc[i][j] = (f32x4){0.f, 0.f, 0.f, 0.f};

  #pragma unroll
  for (int ks = 0; ks < 8; ks++) {
    bf16x8 af[2], bfr[2];
    #pragma unroll
    for (int i = 0; i < 2; i++)
      af[i] = *(const bf16x8*)(As + (i * 16 + ln) * 264 + ks * 32 + quad * 8);
    #pragma unroll
    for (int j = 0; j < 2; j++)
      bfr[j] = *(const bf16x8*)(weff + (size_t)(nq + j * 16 + ln) * FEAT +
                                ks * 32 + quad * 8);
    #pragma unroll
    for (int i = 0; i < 2; i++)
      #pragma unroll
      for (int j = 0; j < 2; j++)
        acc[i][j] = mfma16(af[i], bfr[j], acc[i][j]);
  }

  #pragma unroll
  for (int j = 0; j < 2; j++) {
    const int gn = nq + j * 16 + ln;
    const float bb = beff[gn];
    float s = 0.f, q = 0.f;
    #pragma unroll
    for (int i = 0; i < 2; i++) {
      u16x4 pk;
      #pragma unroll
      for (int r = 0; r < 4; r++) {
        const int gm = m0 + i * 16 + quad * 4 + r;
        float v = acc[i][j][r] + bb;
        const size_t idx = (size_t)gm * DIM + gn;
        if (mode == 0) {
          v = v > 0.f ? v : expm1f(v);
          const unsigned short h = f2bf(v);
          ((unsigned short*)outv)[idx] = h;
          pk[r] = h;
          const float hv = bf2f(h);
          s += hv; q += hv * hv;
        } else {
          v += bf2f(resid[idx]);
          if (is32) ((float*)outv)[idx] = v;
          else      ((unsigned short*)outv)[idx] = f2bf(v);
        }
      }
      if (mode == 0)
        *(u16x4*)(xTout + (size_t)gn * NROWS + m0 + i * 16 + quad * 4) = pk;
    }
    if (mode == 0) {
      s += __shfl_xor(s, 16); q += __shfl_xor(q, 16);
      s += __shfl_xor(s, 32); q += __shfl_xor(q, 32);
      if (quad == 0) {
        atomicAdd(&statsOut[gn], s);
        atomicAdd(&statsOut[256 + gn], q);
      }
    }
  }
}

// ---------------------------------------------------------------------------
extern "C" void kernel_launch(void* const* d_in, const int* in_sizes, int n_in,
                              void* d_out, int out_size, void* d_ws, size_t ws_size,
                              hipStream_t stream) {
  const void* Lm   = d_in[0];
  // d_in[1] = mask (unused)
  const void* inp  = d_in[2];
  const void* bn0g = d_in[3];
  const void* bn0b = d_in[4];
  const void* fc0w = d_in[5];
  const void* fc0b = d_in[6];
  const void* bn1g = d_in[7];
  const void* bn1b = d_in[8];
  const void* fc1w = d_in[9];
  const void* fc1b = d_in[10];

  char* ws = (char*)d_ws;
  unsigned short* xT   = (unsigned short*)(ws);                  // 2 MB
  unsigned short* x0   = (unsigned short*)(ws + (2ull << 20));   // 2 MB
  unsigned short* Lxb  = (unsigned short*)(ws + (4ull << 20));   // 2 MB
  unsigned short* x1   = (unsigned short*)(ws + (6ull << 20));   // 2 MB
  unsigned short* inpc = (unsigned short*)(ws + (8ull << 20));   // 2 MB
  float*          stats= (float*)         (ws + (10ull << 20));  // 2x512 f32
  int*            flag = (int*)           (ws + (10ull << 20) + 8192);
  float*          beff = (float*)         (ws + (10ull << 20) + 12288);
  unsigned short* weff = (unsigned short*)(ws + (10ull << 20) + 16384); // 64KB

  detect_kernel<<<1, 256, 0, stream>>>((const unsigned short*)Lm, flag, stats);

  // ---- block 0 ----
  trans_kernel<<<64, 256, 0, stream>>>(inp, xT, x0, inpc, stats, flag);
  gemm1_fused<<<256, 512, 0, stream>>>(Lm, xT, Lxb, stats, flag);
  prep_kernel<<<128, 256, 0, stream>>>(stats, bn0g, bn0b, fc0w, fc0b,
                                       weff, beff, flag);
  gemm2_fc<<<256, 256, 0, stream>>>(x0, Lxb, weff, beff, nullptr, x1,
                                    xT, stats + 512, 0, flag);

  // ---- block 1 ----
  gemm1_fused<<<256, 512, 0, stream>>>(Lm, xT, Lxb, stats + 512, flag);
  prep_kernel<<<128, 256, 0, stream>>>(stats + 512, bn1g, bn1b, fc1w, fc1b,
                                       weff, beff, flag);
  gemm2_fc<<<256, 256, 0, stream>>>(x1, Lxb, weff, beff, inpc, d_out,
                                    nullptr, nullptr, 1, flag);
}